// Round 5
// baseline (957.841 us; speedup 1.0000x reference)
//
#include <hip/hip_runtime.h>

#define NPTS 16384
#define DIN  1024
#define DP   128
#define NS   163
#define NBLK 256         // one wave per block, one block per CU
#define BTHR 64          // NBLK*BTHR = NPTS, 1 point/thread

// ---------------- K1: projection GEMM  R[N,128] = F[N,1024] @ W[1024,128] (f32)
__global__ __launch_bounds__(256) void k_proj(const float* __restrict__ F,
                                              const float* __restrict__ W,
                                              float* __restrict__ R) {
    __shared__ float As[32][36];    // 32 rows x 32 k (+pad, 36 keeps 16B align)
    __shared__ float Bs[32][128];   // 32 k x 128 cols
    const int tid = threadIdx.x;
    const int bm  = blockIdx.x;            // 512 blocks * 32 rows
    const int lr  = tid >> 3;              // A-load row 0..31
    const int lc  = (tid & 7) * 4;         // A-load k-offset
    const int bkr = tid >> 5;              // B-load kk base 0..7
    const int bc  = (tid & 31) * 4;        // B-load col
    const int r0  = (tid >> 5) * 4;        // 0,4,..,28
    const int c0  = (tid & 31) * 4;        // 0,4,..,124

    float acc[4][4] = {};

    for (int k0 = 0; k0 < DIN; k0 += 32) {
        __syncthreads();
        *(float4*)&As[lr][lc] =
            *(const float4*)&F[(size_t)(bm * 32 + lr) * DIN + k0 + lc];
        #pragma unroll
        for (int p = 0; p < 4; ++p) {
            const int kk = bkr + p * 8;
            *(float4*)&Bs[kk][bc] = *(const float4*)&W[(size_t)(k0 + kk) * DP + bc];
        }
        __syncthreads();
        #pragma unroll
        for (int kt = 0; kt < 32; kt += 4) {
            float4 a[4], b[4];
            #pragma unroll
            for (int i = 0; i < 4; ++i) a[i] = *(const float4*)&As[r0 + i][kt];
            #pragma unroll
            for (int j = 0; j < 4; ++j) b[j] = *(const float4*)&Bs[kt + j][c0];
            #pragma unroll
            for (int i = 0; i < 4; ++i) {
                acc[i][0] += a[i].x * b[0].x; acc[i][1] += a[i].x * b[0].y;
                acc[i][2] += a[i].x * b[0].z; acc[i][3] += a[i].x * b[0].w;
                acc[i][0] += a[i].y * b[1].x; acc[i][1] += a[i].y * b[1].y;
                acc[i][2] += a[i].y * b[1].z; acc[i][3] += a[i].y * b[1].w;
                acc[i][0] += a[i].z * b[2].x; acc[i][1] += a[i].z * b[2].y;
                acc[i][2] += a[i].z * b[2].z; acc[i][3] += a[i].z * b[2].w;
                acc[i][0] += a[i].w * b[3].x; acc[i][1] += a[i].w * b[3].y;
                acc[i][2] += a[i].w * b[3].z; acc[i][3] += a[i].w * b[3].w;
            }
        }
    }
    #pragma unroll
    for (int i = 0; i < 4; ++i) {
        float4 v = make_float4(acc[i][0], acc[i][1], acc[i][2], acc[i][3]);
        *(float4*)&R[(size_t)(bm * 32 + r0 + i) * DP + c0] = v;
    }
}

// ---------------- K2: per-row squared norm sq[i] = ||R_i||^2 (wave per row)
__global__ void k_sq(const float* __restrict__ R, float* __restrict__ sq) {
    const int lane = threadIdx.x & 63;
    const int wave = (blockIdx.x * blockDim.x + threadIdx.x) >> 6;  // 0..255
    for (int row = wave; row < NPTS; row += 256) {
        const float a = R[(size_t)row * DP + lane];
        const float b = R[(size_t)row * DP + 64 + lane];
        float v = a * a + b * b;
        #pragma unroll
        for (int off = 32; off; off >>= 1) v += __shfl_xor(v, off);
        if (lane == 0) sq[row] = v;
    }
}

// ---------------- K3a: coalesced partial col sums over 256-row slabs; also clears gmax
__global__ __launch_bounds__(256) void k_colpart(const float* __restrict__ R,
                                                 const float* __restrict__ sq,
                                                 float* __restrict__ part,
                                                 float* __restrict__ part_sq,
                                                 unsigned long long* __restrict__ gmax) {
    const int b = blockIdx.x, tid = threadIdx.x;

    // clear the greedy slots: NS*NBLK = 41728 slots, 16384 threads -> 3 strides
    for (int s = b * 256 + tid; s < NS * NBLK; s += 64 * 256) gmax[s] = 0ull;

    if (tid < DP) {
        float acc = 0.0f;
        const float* p = R + (size_t)b * 256 * DP + tid;
        #pragma unroll 8
        for (int r = 0; r < 256; ++r) acc += p[(size_t)r * DP];
        part[b * DP + tid] = acc;
    } else if (tid < 192) {
        const int lane = tid - 128;   // wave 2: partial sum of sq over the slab
        const float* s = sq + b * 256;
        float v = s[lane] + s[64 + lane] + s[128 + lane] + s[192 + lane];
        #pragma unroll
        for (int off = 32; off; off >>= 1) v += __shfl_xor(v, off);
        if (lane == 0) part_sq[b] = v;
    }
}

// ---------------- K3b: final deterministic reduction of partials
__global__ void k_colfin(const float* __restrict__ part, const float* __restrict__ part_sq,
                         float* __restrict__ tS) {
    const int tid = threadIdx.x;
    if (tid < DP) {
        float acc = 0.0f;
        #pragma unroll 8
        for (int b = 0; b < 64; ++b) acc += part[b * DP + tid];
        tS[tid] = acc;
    } else if (tid == DP) {
        float s = 0.0f;
        #pragma unroll
        for (int b = 0; b < 64; ++b) s += part_sq[b];
        tS[DP] = s;
    }
}

// ---------------- K4: greedy FPS; 1 wave/block, zero LDS, zero __syncthreads
__global__ __launch_bounds__(BTHR, 1) void k_greedy(
    const float* __restrict__ R, const float* __restrict__ sq,
    const float* __restrict__ tS, const float* __restrict__ F,
    unsigned long long* gmax, float* __restrict__ out) {
    const int tid = threadIdx.x;                // 0..63 == lane
    const int bid = blockIdx.x;                 // 0..255
    const int g   = (bid << 6) | tid;           // my point id

    // own projected row in registers (32 x float4 = 128 VGPRs)
    float4 rr[32];
    #pragma unroll
    for (int q = 0; q < 32; ++q) rr[q] = *(const float4*)&R[(size_t)g * DP + q * 4];
    const float sqi = sq[g];

    // anchor0 = sqrt(N*sq_i + S - 2*r_i.t)  (common terms preserve ranking)
    float a0 = 0.f, a1 = 0.f, a2 = 0.f, a3 = 0.f;
    #pragma unroll
    for (int q = 0; q < 32; ++q) {
        const float4 t4 = *(const float4*)&tS[q * 4];
        a0 += rr[q].x * t4.x; a1 += rr[q].y * t4.y;
        a2 += rr[q].z * t4.z; a3 += rr[q].w * t4.w;
    }
    const float S = tS[DP];
    float anchor = sqrtf(fmaxf((float)NPTS * sqi + S - 2.0f * ((a0 + a1) + (a2 + a3)), 0.0f));

    unsigned myidx = 0;

    for (int k = 0; k < NS; ++k) {
        // key = (bits(anchor)<<32) | (~g): max-key == first-occurrence argmax; never 0
        unsigned long long key =
            ((unsigned long long)__float_as_uint(anchor) << 32) |
            (unsigned long long)(0xFFFFFFFFu - (unsigned)g);
        #pragma unroll
        for (int off = 32; off; off >>= 1) {
            const unsigned long long o = __shfl_xor(key, off);
            key = (o > key) ? o : key;
        }
        // publish this block's max directly (no LDS hop, no syncthreads)
        if (tid == 0)
            __hip_atomic_store(&gmax[(size_t)k * NBLK + bid], key,
                               __ATOMIC_RELAXED, __HIP_MEMORY_SCOPE_AGENT);

        // poll all 256 slots: 4 loads/lane, sleep backoff
        const unsigned long long* gs = &gmax[(size_t)k * NBLK];
        unsigned long long v0, v1, v2, v3;
        v0 = __hip_atomic_load(&gs[tid      ], __ATOMIC_RELAXED, __HIP_MEMORY_SCOPE_AGENT);
        v1 = __hip_atomic_load(&gs[tid +  64], __ATOMIC_RELAXED, __HIP_MEMORY_SCOPE_AGENT);
        v2 = __hip_atomic_load(&gs[tid + 128], __ATOMIC_RELAXED, __HIP_MEMORY_SCOPE_AGENT);
        v3 = __hip_atomic_load(&gs[tid + 192], __ATOMIC_RELAXED, __HIP_MEMORY_SCOPE_AGENT);
        while (!__all((v0 != 0ull) & (v1 != 0ull) & (v2 != 0ull) & (v3 != 0ull))) {
            __builtin_amdgcn_s_sleep(1);
            v0 = __hip_atomic_load(&gs[tid      ], __ATOMIC_RELAXED, __HIP_MEMORY_SCOPE_AGENT);
            v1 = __hip_atomic_load(&gs[tid +  64], __ATOMIC_RELAXED, __HIP_MEMORY_SCOPE_AGENT);
            v2 = __hip_atomic_load(&gs[tid + 128], __ATOMIC_RELAXED, __HIP_MEMORY_SCOPE_AGENT);
            v3 = __hip_atomic_load(&gs[tid + 192], __ATOMIC_RELAXED, __HIP_MEMORY_SCOPE_AGENT);
        }

        unsigned long long m = v0;
        if (v1 > m) m = v1;
        if (v2 > m) m = v2;
        if (v3 > m) m = v3;
        #pragma unroll
        for (int off = 32; off; off >>= 1) {
            const unsigned long long o = __shfl_xor(m, off);
            m = (o > m) ? o : m;
        }
        const unsigned idx = 0xFFFFFFFFu - (unsigned)(m & 0xFFFFFFFFull);
        if (k == bid) myidx = idx;   // block k gathers row k at the end

        // anchor = min(anchor, dist(g, idx)); selected row via broadcast loads
        const float sqs = sq[idx];
        const float* rs = &R[(size_t)idx * DP];
        float d0 = 0.f, d1 = 0.f, d2 = 0.f, d3 = 0.f;
        #pragma unroll
        for (int q = 0; q < 32; ++q) {
            const float4 w4 = *(const float4*)&rs[q * 4];
            d0 += rr[q].x * w4.x; d1 += rr[q].y * w4.y;
            d2 += rr[q].z * w4.z; d3 += rr[q].w * w4.w;
        }
        const float d = sqrtf(fmaxf(sqi + sqs - 2.0f * ((d0 + d1) + (d2 + d3)), 0.0f));
        anchor = fminf(anchor, d);

        // loop-carried register pin: rr appears modified each iteration ->
        // cannot be rematerialized from R
        #pragma unroll
        for (int q = 0; q < 32; ++q)
            asm volatile("" : "+v"(rr[q].x), "+v"(rr[q].y), "+v"(rr[q].z), "+v"(rr[q].w));
    }

    // gather: block k writes out[k] = F[idx_k]  (no LDS needed, idx in register)
    if (bid < NS) {
        #pragma unroll
        for (int p = 0; p < DIN / (BTHR * 4); ++p) {
            const int c = (p * BTHR + tid) * 4;
            *(float4*)&out[(size_t)bid * DIN + c] =
                *(const float4*)&F[(size_t)myidx * DIN + c];
        }
    }
}

extern "C" void kernel_launch(void* const* d_in, const int* in_sizes, int n_in,
                              void* d_out, int out_size, void* d_ws, size_t ws_size,
                              hipStream_t stream) {
    const float* F = (const float*)d_in[0];   // [16384,1024]
    const float* W = (const float*)d_in[1];   // [1024,128]
    float* out = (float*)d_out;               // [163,1024]

    float* R       = (float*)d_ws;                    // 16384*128 f32 = 8 MiB
    float* sq      = R + (size_t)NPTS * DP;           // 16384 f32
    float* tS      = sq + NPTS;                       // 129 f32 (pad to 132)
    float* part    = tS + 132;                        // 64*128 f32
    float* part_sq = part + 64 * DP;                  // 64 f32
    unsigned long long* gmax = (unsigned long long*)(part_sq + 64);  // NS*NBLK u64

    hipLaunchKernelGGL(k_proj, dim3(NPTS / 32), dim3(256), 0, stream, F, W, R);
    hipLaunchKernelGGL(k_sq, dim3(64), dim3(256), 0, stream, R, sq);
    hipLaunchKernelGGL(k_colpart, dim3(64), dim3(256), 0, stream, R, sq, part, part_sq, gmax);
    hipLaunchKernelGGL(k_colfin, dim3(1), dim3(256), 0, stream, part, part_sq, tS);

    const float* Rc = R; const float* sqc = sq; const float* tSc = tS; const float* Fc = F;
    unsigned long long* gm = gmax; float* op = out;
    void* args[] = { (void*)&Rc, (void*)&sqc, (void*)&tSc, (void*)&Fc,
                     (void*)&gm, (void*)&op };
    hipLaunchCooperativeKernel((const void*)k_greedy, dim3(NBLK), dim3(BTHR),
                               args, 0, stream);
}

// Round 6
// 950.503 us; speedup vs baseline: 1.0077x; 1.0077x over previous
//
#include <hip/hip_runtime.h>

#define NPTS 16384
#define DIN  1024
#define DP   128
#define NS   163
#define NBLK 256         // one wave per block, one block per CU
#define BTHR 64          // NBLK*BTHR = NPTS, 1 point/thread

// ---------------- K1: projection GEMM  R[N,128] = F[N,1024] @ W[1024,128] (f32)
__global__ __launch_bounds__(256) void k_proj(const float* __restrict__ F,
                                              const float* __restrict__ W,
                                              float* __restrict__ R) {
    __shared__ float As[32][36];    // 32 rows x 32 k (+pad, 36 keeps 16B align)
    __shared__ float Bs[32][128];   // 32 k x 128 cols
    const int tid = threadIdx.x;
    const int bm  = blockIdx.x;            // 512 blocks * 32 rows
    const int lr  = tid >> 3;              // A-load row 0..31
    const int lc  = (tid & 7) * 4;         // A-load k-offset
    const int bkr = tid >> 5;              // B-load kk base 0..7
    const int bc  = (tid & 31) * 4;        // B-load col
    const int r0  = (tid >> 5) * 4;        // 0,4,..,28
    const int c0  = (tid & 31) * 4;        // 0,4,..,124

    float acc[4][4] = {};

    for (int k0 = 0; k0 < DIN; k0 += 32) {
        __syncthreads();
        *(float4*)&As[lr][lc] =
            *(const float4*)&F[(size_t)(bm * 32 + lr) * DIN + k0 + lc];
        #pragma unroll
        for (int p = 0; p < 4; ++p) {
            const int kk = bkr + p * 8;
            *(float4*)&Bs[kk][bc] = *(const float4*)&W[(size_t)(k0 + kk) * DP + bc];
        }
        __syncthreads();
        #pragma unroll
        for (int kt = 0; kt < 32; kt += 4) {
            float4 a[4], b[4];
            #pragma unroll
            for (int i = 0; i < 4; ++i) a[i] = *(const float4*)&As[r0 + i][kt];
            #pragma unroll
            for (int j = 0; j < 4; ++j) b[j] = *(const float4*)&Bs[kt + j][c0];
            #pragma unroll
            for (int i = 0; i < 4; ++i) {
                acc[i][0] += a[i].x * b[0].x; acc[i][1] += a[i].x * b[0].y;
                acc[i][2] += a[i].x * b[0].z; acc[i][3] += a[i].x * b[0].w;
                acc[i][0] += a[i].y * b[1].x; acc[i][1] += a[i].y * b[1].y;
                acc[i][2] += a[i].y * b[1].z; acc[i][3] += a[i].y * b[1].w;
                acc[i][0] += a[i].z * b[2].x; acc[i][1] += a[i].z * b[2].y;
                acc[i][2] += a[i].z * b[2].z; acc[i][3] += a[i].z * b[2].w;
                acc[i][0] += a[i].w * b[3].x; acc[i][1] += a[i].w * b[3].y;
                acc[i][2] += a[i].w * b[3].z; acc[i][3] += a[i].w * b[3].w;
            }
        }
    }
    #pragma unroll
    for (int i = 0; i < 4; ++i) {
        float4 v = make_float4(acc[i][0], acc[i][1], acc[i][2], acc[i][3]);
        *(float4*)&R[(size_t)(bm * 32 + r0 + i) * DP + c0] = v;
    }
}

// ---------------- K2: per-row squared norm sq[i] = ||R_i||^2 (wave per row)
__global__ void k_sq(const float* __restrict__ R, float* __restrict__ sq) {
    const int lane = threadIdx.x & 63;
    const int wave = (blockIdx.x * blockDim.x + threadIdx.x) >> 6;  // 0..255
    for (int row = wave; row < NPTS; row += 256) {
        const float a = R[(size_t)row * DP + lane];
        const float b = R[(size_t)row * DP + 64 + lane];
        float v = a * a + b * b;
        #pragma unroll
        for (int off = 32; off; off >>= 1) v += __shfl_xor(v, off);
        if (lane == 0) sq[row] = v;
    }
}

// ---------------- K3a: coalesced partial col sums over 256-row slabs; also clears gmax
__global__ __launch_bounds__(256) void k_colpart(const float* __restrict__ R,
                                                 const float* __restrict__ sq,
                                                 float* __restrict__ part,
                                                 float* __restrict__ part_sq,
                                                 unsigned long long* __restrict__ gmax) {
    const int b = blockIdx.x, tid = threadIdx.x;

    // clear the greedy slots: NS*NBLK = 41728 slots, 16384 threads -> 3 strides
    for (int s = b * 256 + tid; s < NS * NBLK; s += 64 * 256) gmax[s] = 0ull;

    if (tid < DP) {
        float acc = 0.0f;
        const float* p = R + (size_t)b * 256 * DP + tid;
        #pragma unroll 8
        for (int r = 0; r < 256; ++r) acc += p[(size_t)r * DP];
        part[b * DP + tid] = acc;
    } else if (tid < 192) {
        const int lane = tid - 128;   // wave 2: partial sum of sq over the slab
        const float* s = sq + b * 256;
        float v = s[lane] + s[64 + lane] + s[128 + lane] + s[192 + lane];
        #pragma unroll
        for (int off = 32; off; off >>= 1) v += __shfl_xor(v, off);
        if (lane == 0) part_sq[b] = v;
    }
}

// ---------------- K3b: final deterministic reduction of partials
__global__ void k_colfin(const float* __restrict__ part, const float* __restrict__ part_sq,
                         float* __restrict__ tS) {
    const int tid = threadIdx.x;
    if (tid < DP) {
        float acc = 0.0f;
        #pragma unroll 8
        for (int b = 0; b < 64; ++b) acc += part[b * DP + tid];
        tS[tid] = acc;
    } else if (tid == DP) {
        float s = 0.0f;
        #pragma unroll
        for (int b = 0; b < 64; ++b) s += part_sq[b];
        tS[DP] = s;
    }
}

// ---------------- K4: greedy FPS; 1 wave/block, zero LDS, zero __syncthreads
__global__ __launch_bounds__(BTHR, 1) void k_greedy(
    const float* __restrict__ R, const float* __restrict__ sq,
    const float* __restrict__ tS, const float* __restrict__ F,
    unsigned long long* gmax, float* __restrict__ out) {
    const int tid = threadIdx.x;                // 0..63 == lane
    const int bid = blockIdx.x;                 // 0..255
    const int g   = (bid << 6) | tid;           // my point id

    // own projected row in registers (32 x float4 = 128 VGPRs)
    float4 rr[32];
    #pragma unroll
    for (int q = 0; q < 32; ++q) rr[q] = *(const float4*)&R[(size_t)g * DP + q * 4];
    const float sqi = sq[g];

    // anchor0 = sqrt(N*sq_i + S - 2*r_i.t)  (common terms preserve ranking)
    float a0 = 0.f, a1 = 0.f, a2 = 0.f, a3 = 0.f;
    #pragma unroll
    for (int q = 0; q < 32; ++q) {
        const float4 t4 = *(const float4*)&tS[q * 4];
        a0 += rr[q].x * t4.x; a1 += rr[q].y * t4.y;
        a2 += rr[q].z * t4.z; a3 += rr[q].w * t4.w;
    }
    const float S = tS[DP];
    float anchor = sqrtf(fmaxf((float)NPTS * sqi + S - 2.0f * ((a0 + a1) + (a2 + a3)), 0.0f));

    unsigned myidx = 0;

    for (int k = 0; k < NS; ++k) {
        // key = (bits(anchor)<<32) | (~g): max-key == first-occurrence argmax; never 0
        unsigned long long key =
            ((unsigned long long)__float_as_uint(anchor) << 32) |
            (unsigned long long)(0xFFFFFFFFu - (unsigned)g);
        #pragma unroll
        for (int off = 32; off; off >>= 1) {
            const unsigned long long o = __shfl_xor(key, off);
            key = (o > key) ? o : key;
        }
        // publish this block's max directly (no LDS hop, no syncthreads)
        if (tid == 0)
            __hip_atomic_store(&gmax[(size_t)k * NBLK + bid], key,
                               __ATOMIC_RELAXED, __HIP_MEMORY_SCOPE_AGENT);

        // poll all 256 slots: 4 loads/lane, sleep backoff
        const unsigned long long* gs = &gmax[(size_t)k * NBLK];
        unsigned long long v0, v1, v2, v3;
        v0 = __hip_atomic_load(&gs[tid      ], __ATOMIC_RELAXED, __HIP_MEMORY_SCOPE_AGENT);
        v1 = __hip_atomic_load(&gs[tid +  64], __ATOMIC_RELAXED, __HIP_MEMORY_SCOPE_AGENT);
        v2 = __hip_atomic_load(&gs[tid + 128], __ATOMIC_RELAXED, __HIP_MEMORY_SCOPE_AGENT);
        v3 = __hip_atomic_load(&gs[tid + 192], __ATOMIC_RELAXED, __HIP_MEMORY_SCOPE_AGENT);
        while (!__all((v0 != 0ull) & (v1 != 0ull) & (v2 != 0ull) & (v3 != 0ull))) {
            __builtin_amdgcn_s_sleep(1);
            v0 = __hip_atomic_load(&gs[tid      ], __ATOMIC_RELAXED, __HIP_MEMORY_SCOPE_AGENT);
            v1 = __hip_atomic_load(&gs[tid +  64], __ATOMIC_RELAXED, __HIP_MEMORY_SCOPE_AGENT);
            v2 = __hip_atomic_load(&gs[tid + 128], __ATOMIC_RELAXED, __HIP_MEMORY_SCOPE_AGENT);
            v3 = __hip_atomic_load(&gs[tid + 192], __ATOMIC_RELAXED, __HIP_MEMORY_SCOPE_AGENT);
        }

        unsigned long long m = v0;
        if (v1 > m) m = v1;
        if (v2 > m) m = v2;
        if (v3 > m) m = v3;
        #pragma unroll
        for (int off = 32; off; off >>= 1) {
            const unsigned long long o = __shfl_xor(m, off);
            m = (o > m) ? o : m;
        }
        const unsigned idx = 0xFFFFFFFFu - (unsigned)(m & 0xFFFFFFFFull);
        if (k == bid) myidx = idx;   // block k gathers row k at the end

        // anchor = min(anchor, dist(g, idx)); selected row via broadcast loads
        const float sqs = sq[idx];
        const float* rs = &R[(size_t)idx * DP];
        float d0 = 0.f, d1 = 0.f, d2 = 0.f, d3 = 0.f;
        #pragma unroll
        for (int q = 0; q < 32; ++q) {
            const float4 w4 = *(const float4*)&rs[q * 4];
            d0 += rr[q].x * w4.x; d1 += rr[q].y * w4.y;
            d2 += rr[q].z * w4.z; d3 += rr[q].w * w4.w;
        }
        const float d = sqrtf(fmaxf(sqi + sqs - 2.0f * ((d0 + d1) + (d2 + d3)), 0.0f));
        anchor = fminf(anchor, d);

        // loop-carried register pin: rr appears modified each iteration ->
        // cannot be rematerialized from R
        #pragma unroll
        for (int q = 0; q < 32; ++q)
            asm volatile("" : "+v"(rr[q].x), "+v"(rr[q].y), "+v"(rr[q].z), "+v"(rr[q].w));
    }

    // gather: block k writes out[k] = F[idx_k]  (no LDS needed, idx in register)
    if (bid < NS) {
        #pragma unroll
        for (int p = 0; p < DIN / (BTHR * 4); ++p) {
            const int c = (p * BTHR + tid) * 4;
            *(float4*)&out[(size_t)bid * DIN + c] =
                *(const float4*)&F[(size_t)myidx * DIN + c];
        }
    }
}

extern "C" void kernel_launch(void* const* d_in, const int* in_sizes, int n_in,
                              void* d_out, int out_size, void* d_ws, size_t ws_size,
                              hipStream_t stream) {
    const float* F = (const float*)d_in[0];   // [16384,1024]
    const float* W = (const float*)d_in[1];   // [1024,128]
    float* out = (float*)d_out;               // [163,1024]

    float* R       = (float*)d_ws;                    // 16384*128 f32 = 8 MiB
    float* sq      = R + (size_t)NPTS * DP;           // 16384 f32
    float* tS      = sq + NPTS;                       // 129 f32 (pad to 132)
    float* part    = tS + 132;                        // 64*128 f32
    float* part_sq = part + 64 * DP;                  // 64 f32
    unsigned long long* gmax = (unsigned long long*)(part_sq + 64);  // NS*NBLK u64

    hipLaunchKernelGGL(k_proj, dim3(NPTS / 32), dim3(256), 0, stream, F, W, R);
    hipLaunchKernelGGL(k_sq, dim3(64), dim3(256), 0, stream, R, sq);
    hipLaunchKernelGGL(k_colpart, dim3(64), dim3(256), 0, stream, R, sq, part, part_sq, gmax);
    hipLaunchKernelGGL(k_colfin, dim3(1), dim3(256), 0, stream, part, part_sq, tS);

    const float* Rc = R; const float* sqc = sq; const float* tSc = tS; const float* Fc = F;
    unsigned long long* gm = gmax; float* op = out;
    void* args[] = { (void*)&Rc, (void*)&sqc, (void*)&tSc, (void*)&Fc,
                     (void*)&gm, (void*)&op };
    hipLaunchCooperativeKernel((const void*)k_greedy, dim3(NBLK), dim3(BTHR),
                               args, 0, stream);
}

// Round 7
// 950.104 us; speedup vs baseline: 1.0081x; 1.0004x over previous
//
#include <hip/hip_runtime.h>

#define NPTS 16384
#define DIN  1024
#define DP   128
#define NS   163
#define NBLK 256         // one wave per block, one block per CU
#define BTHR 64          // NBLK*BTHR = NPTS, 1 point/thread

// ---------------- K1: projection GEMM  R[N,128] = F[N,1024] @ W[1024,128] (f32)
__global__ __launch_bounds__(256) void k_proj(const float* __restrict__ F,
                                              const float* __restrict__ W,
                                              float* __restrict__ R) {
    __shared__ float As[32][36];    // 32 rows x 32 k (+pad, 36 keeps 16B align)
    __shared__ float Bs[32][128];   // 32 k x 128 cols
    const int tid = threadIdx.x;
    const int bm  = blockIdx.x;            // 512 blocks * 32 rows
    const int lr  = tid >> 3;              // A-load row 0..31
    const int lc  = (tid & 7) * 4;         // A-load k-offset
    const int bkr = tid >> 5;              // B-load kk base 0..7
    const int bc  = (tid & 31) * 4;        // B-load col
    const int r0  = (tid >> 5) * 4;        // 0,4,..,28
    const int c0  = (tid & 31) * 4;        // 0,4,..,124

    float acc[4][4] = {};

    for (int k0 = 0; k0 < DIN; k0 += 32) {
        __syncthreads();
        *(float4*)&As[lr][lc] =
            *(const float4*)&F[(size_t)(bm * 32 + lr) * DIN + k0 + lc];
        #pragma unroll
        for (int p = 0; p < 4; ++p) {
            const int kk = bkr + p * 8;
            *(float4*)&Bs[kk][bc] = *(const float4*)&W[(size_t)(k0 + kk) * DP + bc];
        }
        __syncthreads();
        #pragma unroll
        for (int kt = 0; kt < 32; kt += 4) {
            float4 a[4], b[4];
            #pragma unroll
            for (int i = 0; i < 4; ++i) a[i] = *(const float4*)&As[r0 + i][kt];
            #pragma unroll
            for (int j = 0; j < 4; ++j) b[j] = *(const float4*)&Bs[kt + j][c0];
            #pragma unroll
            for (int i = 0; i < 4; ++i) {
                acc[i][0] += a[i].x * b[0].x; acc[i][1] += a[i].x * b[0].y;
                acc[i][2] += a[i].x * b[0].z; acc[i][3] += a[i].x * b[0].w;
                acc[i][0] += a[i].y * b[1].x; acc[i][1] += a[i].y * b[1].y;
                acc[i][2] += a[i].y * b[1].z; acc[i][3] += a[i].y * b[1].w;
                acc[i][0] += a[i].z * b[2].x; acc[i][1] += a[i].z * b[2].y;
                acc[i][2] += a[i].z * b[2].z; acc[i][3] += a[i].z * b[2].w;
                acc[i][0] += a[i].w * b[3].x; acc[i][1] += a[i].w * b[3].y;
                acc[i][2] += a[i].w * b[3].z; acc[i][3] += a[i].w * b[3].w;
            }
        }
    }
    #pragma unroll
    for (int i = 0; i < 4; ++i) {
        float4 v = make_float4(acc[i][0], acc[i][1], acc[i][2], acc[i][3]);
        *(float4*)&R[(size_t)(bm * 32 + r0 + i) * DP + c0] = v;
    }
}

// ---------------- K2: per-row squared norm sq[i] = ||R_i||^2 (wave per row)
__global__ void k_sq(const float* __restrict__ R, float* __restrict__ sq) {
    const int lane = threadIdx.x & 63;
    const int wave = (blockIdx.x * blockDim.x + threadIdx.x) >> 6;  // 0..255
    for (int row = wave; row < NPTS; row += 256) {
        const float a = R[(size_t)row * DP + lane];
        const float b = R[(size_t)row * DP + 64 + lane];
        float v = a * a + b * b;
        #pragma unroll
        for (int off = 32; off; off >>= 1) v += __shfl_xor(v, off);
        if (lane == 0) sq[row] = v;
    }
}

// ---------------- K3a: coalesced partial col sums over 256-row slabs; also clears gmax
__global__ __launch_bounds__(256) void k_colpart(const float* __restrict__ R,
                                                 const float* __restrict__ sq,
                                                 float* __restrict__ part,
                                                 float* __restrict__ part_sq,
                                                 unsigned long long* __restrict__ gmax) {
    const int b = blockIdx.x, tid = threadIdx.x;

    // clear the greedy slots: NS*NBLK = 41728 slots, 16384 threads -> 3 strides
    for (int s = b * 256 + tid; s < NS * NBLK; s += 64 * 256) gmax[s] = 0ull;

    if (tid < DP) {
        float acc = 0.0f;
        const float* p = R + (size_t)b * 256 * DP + tid;
        #pragma unroll 8
        for (int r = 0; r < 256; ++r) acc += p[(size_t)r * DP];
        part[b * DP + tid] = acc;
    } else if (tid < 192) {
        const int lane = tid - 128;   // wave 2: partial sum of sq over the slab
        const float* s = sq + b * 256;
        float v = s[lane] + s[64 + lane] + s[128 + lane] + s[192 + lane];
        #pragma unroll
        for (int off = 32; off; off >>= 1) v += __shfl_xor(v, off);
        if (lane == 0) part_sq[b] = v;
    }
}

// ---------------- K3b: final deterministic reduction of partials
__global__ void k_colfin(const float* __restrict__ part, const float* __restrict__ part_sq,
                         float* __restrict__ tS) {
    const int tid = threadIdx.x;
    if (tid < DP) {
        float acc = 0.0f;
        #pragma unroll 8
        for (int b = 0; b < 64; ++b) acc += part[b * DP + tid];
        tS[tid] = acc;
    } else if (tid == DP) {
        float s = 0.0f;
        #pragma unroll
        for (int b = 0; b < 64; ++b) s += part_sq[b];
        tS[DP] = s;
    }
}

// ---------------- K4: greedy FPS; 1 wave/block, zero LDS, zero __syncthreads
__global__ __launch_bounds__(BTHR, 1) void k_greedy(
    const float* __restrict__ R, const float* __restrict__ sq,
    const float* __restrict__ tS, const float* __restrict__ F,
    unsigned long long* gmax, float* __restrict__ out) {
    const int tid = threadIdx.x;                // 0..63 == lane
    const int bid = blockIdx.x;                 // 0..255
    const int g   = (bid << 6) | tid;           // my point id

    // own projected row in registers (32 x float4 = 128 VGPRs)
    float4 rr[32];
    #pragma unroll
    for (int q = 0; q < 32; ++q) rr[q] = *(const float4*)&R[(size_t)g * DP + q * 4];
    const float sqi = sq[g];

    // anchor0 = sqrt(N*sq_i + S - 2*r_i.t)  (common terms preserve ranking)
    float a0 = 0.f, a1 = 0.f, a2 = 0.f, a3 = 0.f;
    #pragma unroll
    for (int q = 0; q < 32; ++q) {
        const float4 t4 = *(const float4*)&tS[q * 4];
        a0 += rr[q].x * t4.x; a1 += rr[q].y * t4.y;
        a2 += rr[q].z * t4.z; a3 += rr[q].w * t4.w;
    }
    const float S = tS[DP];
    float anchor = sqrtf(fmaxf((float)NPTS * sqi + S - 2.0f * ((a0 + a1) + (a2 + a3)), 0.0f));

    unsigned myidx = 0;

    for (int k = 0; k < NS; ++k) {
        // key = (bits(anchor)<<32) | (~g): max-key == first-occurrence argmax; never 0
        unsigned long long key =
            ((unsigned long long)__float_as_uint(anchor) << 32) |
            (unsigned long long)(0xFFFFFFFFu - (unsigned)g);
        #pragma unroll
        for (int off = 32; off; off >>= 1) {
            const unsigned long long o = __shfl_xor(key, off);
            key = (o > key) ? o : key;
        }
        // publish this block's max directly (no LDS hop, no syncthreads)
        if (tid == 0)
            __hip_atomic_store(&gmax[(size_t)k * NBLK + bid], key,
                               __ATOMIC_RELAXED, __HIP_MEMORY_SCOPE_AGENT);

        // poll all 256 slots: 4 loads/lane, sleep backoff
        const unsigned long long* gs = &gmax[(size_t)k * NBLK];
        unsigned long long v0, v1, v2, v3;
        v0 = __hip_atomic_load(&gs[tid      ], __ATOMIC_RELAXED, __HIP_MEMORY_SCOPE_AGENT);
        v1 = __hip_atomic_load(&gs[tid +  64], __ATOMIC_RELAXED, __HIP_MEMORY_SCOPE_AGENT);
        v2 = __hip_atomic_load(&gs[tid + 128], __ATOMIC_RELAXED, __HIP_MEMORY_SCOPE_AGENT);
        v3 = __hip_atomic_load(&gs[tid + 192], __ATOMIC_RELAXED, __HIP_MEMORY_SCOPE_AGENT);
        while (!__all((v0 != 0ull) & (v1 != 0ull) & (v2 != 0ull) & (v3 != 0ull))) {
            __builtin_amdgcn_s_sleep(1);
            v0 = __hip_atomic_load(&gs[tid      ], __ATOMIC_RELAXED, __HIP_MEMORY_SCOPE_AGENT);
            v1 = __hip_atomic_load(&gs[tid +  64], __ATOMIC_RELAXED, __HIP_MEMORY_SCOPE_AGENT);
            v2 = __hip_atomic_load(&gs[tid + 128], __ATOMIC_RELAXED, __HIP_MEMORY_SCOPE_AGENT);
            v3 = __hip_atomic_load(&gs[tid + 192], __ATOMIC_RELAXED, __HIP_MEMORY_SCOPE_AGENT);
        }

        unsigned long long m = v0;
        if (v1 > m) m = v1;
        if (v2 > m) m = v2;
        if (v3 > m) m = v3;
        #pragma unroll
        for (int off = 32; off; off >>= 1) {
            const unsigned long long o = __shfl_xor(m, off);
            m = (o > m) ? o : m;
        }
        const unsigned idx = 0xFFFFFFFFu - (unsigned)(m & 0xFFFFFFFFull);
        if (k == bid) myidx = idx;   // block k gathers row k at the end

        // anchor = min(anchor, dist(g, idx)); selected row via broadcast loads
        const float sqs = sq[idx];
        const float* rs = &R[(size_t)idx * DP];
        float d0 = 0.f, d1 = 0.f, d2 = 0.f, d3 = 0.f;
        #pragma unroll
        for (int q = 0; q < 32; ++q) {
            const float4 w4 = *(const float4*)&rs[q * 4];
            d0 += rr[q].x * w4.x; d1 += rr[q].y * w4.y;
            d2 += rr[q].z * w4.z; d3 += rr[q].w * w4.w;
        }
        const float d = sqrtf(fmaxf(sqi + sqs - 2.0f * ((d0 + d1) + (d2 + d3)), 0.0f));
        anchor = fminf(anchor, d);

        // loop-carried register pin: rr appears modified each iteration ->
        // cannot be rematerialized from R
        #pragma unroll
        for (int q = 0; q < 32; ++q)
            asm volatile("" : "+v"(rr[q].x), "+v"(rr[q].y), "+v"(rr[q].z), "+v"(rr[q].w));
    }

    // gather: block k writes out[k] = F[idx_k]  (no LDS needed, idx in register)
    if (bid < NS) {
        #pragma unroll
        for (int p = 0; p < DIN / (BTHR * 4); ++p) {
            const int c = (p * BTHR + tid) * 4;
            *(float4*)&out[(size_t)bid * DIN + c] =
                *(const float4*)&F[(size_t)myidx * DIN + c];
        }
    }
}

extern "C" void kernel_launch(void* const* d_in, const int* in_sizes, int n_in,
                              void* d_out, int out_size, void* d_ws, size_t ws_size,
                              hipStream_t stream) {
    const float* F = (const float*)d_in[0];   // [16384,1024]
    const float* W = (const float*)d_in[1];   // [1024,128]
    float* out = (float*)d_out;               // [163,1024]

    float* R       = (float*)d_ws;                    // 16384*128 f32 = 8 MiB
    float* sq      = R + (size_t)NPTS * DP;           // 16384 f32
    float* tS      = sq + NPTS;                       // 129 f32 (pad to 132)
    float* part    = tS + 132;                        // 64*128 f32
    float* part_sq = part + 64 * DP;                  // 64 f32
    unsigned long long* gmax = (unsigned long long*)(part_sq + 64);  // NS*NBLK u64

    hipLaunchKernelGGL(k_proj, dim3(NPTS / 32), dim3(256), 0, stream, F, W, R);
    hipLaunchKernelGGL(k_sq, dim3(64), dim3(256), 0, stream, R, sq);
    hipLaunchKernelGGL(k_colpart, dim3(64), dim3(256), 0, stream, R, sq, part, part_sq, gmax);
    hipLaunchKernelGGL(k_colfin, dim3(1), dim3(256), 0, stream, part, part_sq, tS);

    const float* Rc = R; const float* sqc = sq; const float* tSc = tS; const float* Fc = F;
    unsigned long long* gm = gmax; float* op = out;
    void* args[] = { (void*)&Rc, (void*)&sqc, (void*)&tSc, (void*)&Fc,
                     (void*)&gm, (void*)&op };
    hipLaunchCooperativeKernel((const void*)k_greedy, dim3(NBLK), dim3(BTHR),
                               args, 0, stream);
}